// Round 6
// baseline (83.516 us; speedup 1.0000x reference)
//
#include <hip/hip_runtime.h>
#include <hip/hip_fp16.h>
#include <math.h>

// HybridQuanvolutionEstimator — analytic circuit collapse + bf16 MFMA linear.
//
// z0=cos(a0+th0); z1=cos(th1)*cos(a1); z2=cos(a2); z3=cos(a3+th3)
// qf[b,4p..4p+3] = [z0, z0*z1, z0*z1*z2, z1*z2*z3]
// logits = qf @ lin_w.T + lin_b ; out = log_softmax(logits)
//
// R6 vs R5 (kill the TA-pipe scatter): one conv OUTPUT per thread, spatial
// index fastest -> wave64 float2 loads of x are dense 512B spans (coalesced)
// instead of 8B-per-lane over 2KB spans (32 segments/inst). 1 cos per lane
// (was 4 per task). Patch's 4 angles sit on one quad; z values bounce through
// a tiny fp16 LDS buffer (wave-synchronous, no barrier) to form features.
// No x staging in LDS. MFMA / reduce / softmax phases unchanged from R5.

#define NB   4096
#define BPB  4
#define GRID (NB / BPB)          // 1024
#define RS   808                 // bf16 row stride; rows 16B-aligned

using short8  = __attribute__((ext_vector_type(8))) short;
using float4v = __attribute__((ext_vector_type(4))) float;

__device__ __forceinline__ unsigned short f2bf(float f) {
    unsigned u = __builtin_bit_cast(unsigned, f);
    return (unsigned short)((u + 0x7FFFu + ((u >> 16) & 1u)) >> 16);
}

__global__ __launch_bounds__(256) void hqe_kernel(
    const float* __restrict__ x,       // [B, 784]
    const float* __restrict__ conv_w,  // [4,1,2,2]
    const float* __restrict__ conv_b,  // [4]
    const float* __restrict__ q_theta, // [4]
    const float* __restrict__ lin_w,   // [10, 784]
    const float* __restrict__ lin_b,   // [10]
    float* __restrict__ out)           // [B, 10]
{
    // rows 0..3: qf (A, m=batch); rows 4..13: lin_w bf16 (B, n=output);
    // rows 14..19: allocated, read only into discarded C entries.
    __shared__ __align__(16) unsigned short lds[20 * RS];   // 32320 B
    __shared__ __align__(8)  __half zbuf[BPB * 784];        // 6272 B
    __shared__ __align__(16) float red_s[4 * 16 * 16];      // 4096 B
    __shared__ float lg_s[BPB * 10];
    __shared__ float off_s[BPB];

    const int t = threadIdx.x;
    const int b0 = blockIdx.x * BPB;

    // ---- zero pad cols [784,808) of all 20 rows (12 dwords x 20 rows)
    for (int i = t; i < 20 * 12; i += 256) {
        const int r = i / 12, d = i - 12 * r;
        ((unsigned*)(lds + r * RS + 784))[d] = 0u;
    }

    // ---- stage lin_w -> bf16 B rows (abs rows 4..13)
    {
        const float4* lw4 = (const float4*)lin_w;   // 1960 float4
        for (int i = t; i < 1960; i += 256) {
            const int o = i / 196;
            const int k0 = 4 * (i - 196 * o);
            const float4 v = lw4[i];
            const unsigned lo = f2bf(v.x) | ((unsigned)f2bf(v.y) << 16);
            const unsigned hi = f2bf(v.z) | ((unsigned)f2bf(v.w) << 16);
            *(uint2*)(lds + (4 + o) * RS + k0) = make_uint2(lo, hi);
        }
    }

    const float th0 = q_theta[0];
    const float ct1 = __cosf(q_theta[1]);
    const float th3 = q_theta[3];

    // ---- features: one conv output per thread. i = b*784 + c*196 + s.
    // Consecutive lanes -> consecutive s -> x reads are dense/coalesced.
    // Quad (i&~3 .. i|3) = the 4 angles (wires k=0..3) of one patch.
    for (int i = t; i < BPB * 784; i += 256) {
        const int b = i / 784;
        const int r = i - 784 * b;          // flat feature index c*196+s
        const int c = r / 196;
        const int s = r - 196 * c;
        const int k = i & 3;                // wire index (784, 196 mult of 4)
        const int h = s / 14;
        const int w2 = s - 14 * h;

        const float* xp = x + (size_t)(b0 + b) * 784 + 56 * h + 2 * w2;
        const float2 top = *(const float2*)xp;
        const float2 bot = *(const float2*)(xp + 28);
        const float4 cw = ((const float4*)conv_w)[c];
        const float a = conv_b[c] + top.x * cw.x + top.y * cw.y
                                  + bot.x * cw.z + bot.y * cw.w;

        const float shift = (k == 0) ? th0 : ((k == 3) ? th3 : 0.0f);
        float z = __cosf(a + shift);
        z = (k == 1) ? z * ct1 : z;

        zbuf[i] = __float2half(z);
        // wave-synchronous quad gather (same-wave LDS ops are ordered;
        // compiler keeps write->read order since both touch zbuf)
        const __half2* zq = (const __half2*)(zbuf + (i & ~3));
        const __half2 p01 = zq[0];
        const __half2 p23 = zq[1];
        const float z0 = __low2float(p01);
        const float z1 = __high2float(p01);
        const float z2 = __low2float(p23);
        const float z3 = __high2float(p23);

        const float m01 = z0 * z1;
        const float f = (k == 0) ? z0
                      : (k == 1) ? m01
                      : (k == 2) ? m01 * z2
                                 : z1 * z2 * z3;
        lds[b * RS + r] = f2bf(f);          // qf A-row write (2B, dense)
    }

    __syncthreads();

    // ---- MFMA: K = 25 interleaved 32-tiles; wave wv takes k = 32*(wv+4*kk)
    {
        const int wv = t >> 6;
        const int lane = t & 63;
        const int mrow = lane & 15;
        const int qd = lane >> 4;
        const unsigned short* qrow = lds + mrow * RS + 8 * qd;        // A
        const unsigned short* wrow = lds + (4 + mrow) * RS + 8 * qd;  // B
        float4v acc = {0.f, 0.f, 0.f, 0.f};
#pragma unroll
        for (int kk = 0; kk < 7; ++kk) {
            const int k = 32 * (wv + 4 * kk);
            if (k < 800) {
                const short8 af = *(const short8*)(qrow + k);
                const short8 bf = *(const short8*)(wrow + k);
                acc = __builtin_amdgcn_mfma_f32_16x16x32_bf16(af, bf, acc, 0, 0, 0);
            }
        }
        // C: col = lane&15 (=n), rows = qd*4+reg (=m). Store [wv][n][m].
        *(float4v*)(red_s + (wv * 16 + mrow) * 16 + qd * 4) = acc;
    }

    __syncthreads();

    // ---- reduce 4 partial tiles; keep m<4 (batch), n<10 (outputs)
    {
        const int n = t >> 4;
        const int m = t & 15;
        if (m < BPB && n < 10) {
            const float s = red_s[0 * 256 + n * 16 + m] + red_s[1 * 256 + n * 16 + m]
                          + red_s[2 * 256 + n * 16 + m] + red_s[3 * 256 + n * 16 + m];
            lg_s[m * 10 + n] = s + lin_b[n];
        }
    }

    __syncthreads();

    if (t < BPB) {
        float mx = -INFINITY;
#pragma unroll
        for (int j = 0; j < 10; ++j) mx = fmaxf(mx, lg_s[t * 10 + j]);
        float sum = 0.0f;
#pragma unroll
        for (int j = 0; j < 10; ++j) sum += __expf(lg_s[t * 10 + j] - mx);
        off_s[t] = mx + __logf(sum);
    }

    __syncthreads();

    if (t < BPB * 10) {
        out[(size_t)b0 * 10 + t] = lg_s[t] - off_s[t / 10];
    }
}

extern "C" void kernel_launch(void* const* d_in, const int* in_sizes, int n_in,
                              void* d_out, int out_size, void* d_ws, size_t ws_size,
                              hipStream_t stream) {
    const float* x       = (const float*)d_in[0];
    const float* conv_w  = (const float*)d_in[1];
    const float* conv_b  = (const float*)d_in[2];
    const float* q_theta = (const float*)d_in[3];
    const float* lin_w   = (const float*)d_in[4];
    const float* lin_b   = (const float*)d_in[5];
    float* out = (float*)d_out;

    hqe_kernel<<<dim3(GRID), dim3(256), 0, stream>>>(x, conv_w, conv_b, q_theta,
                                                     lin_w, lin_b, out);
}

// Round 8
// 76.433 us; speedup vs baseline: 1.0927x; 1.0927x over previous
//
#include <hip/hip_runtime.h>
#include <math.h>

// HybridQuanvolutionEstimator — analytic circuit collapse + bf16 MFMA linear.
//
// z0=cos(a0+th0); z1=cos(th1)*cos(a1); z2=cos(a2); z3=cos(a3+th3)
// qf[b,4p..4p+3] = [z0, z0*z1, z0*z1*z2, z1*z2*z3]
// logits = qf @ lin_w.T + lin_b ; out = log_softmax(logits)
//
// R8 = R7 with the DPP ctrl as a template (ICE) parameter — update_dpp
// requires a constant integer dpp_ctrl. Semantics identical to R7's intent:
// dense load mapping (one conv output/thread, s fastest: wave64 float2
// x-loads cover dense 512B spans; 1 cos/lane), patch's 4 wires on one
// lane-quad shared via register-only quad_perm broadcasts (no LDS waits).
// MFMA / reduce / softmax unchanged from R5 (verified).

#define NB   4096
#define BPB  4
#define GRID (NB / BPB)          // 1024
#define RS   808                 // bf16 row stride; rows 16B-aligned

using short8  = __attribute__((ext_vector_type(8))) short;
using float4v = __attribute__((ext_vector_type(4))) float;

__device__ __forceinline__ unsigned short f2bf(float f) {
    unsigned u = __builtin_bit_cast(unsigned, f);
    return (unsigned short)((u + 0x7FFFu + ((u >> 16) & 1u)) >> 16);
}

template <int CTRL>
__device__ __forceinline__ float quadb(float v) {
    // quad_perm broadcast: CTRL 0x00/0x55/0xAA/0xFF -> all lanes get slot j
    return __builtin_bit_cast(float,
        __builtin_amdgcn_update_dpp(0, __builtin_bit_cast(int, v),
                                    CTRL, 0xf, 0xf, true));
}

__global__ __launch_bounds__(256) void hqe_kernel(
    const float* __restrict__ x,       // [B, 784]
    const float* __restrict__ conv_w,  // [4,1,2,2]
    const float* __restrict__ conv_b,  // [4]
    const float* __restrict__ q_theta, // [4]
    const float* __restrict__ lin_w,   // [10, 784]
    const float* __restrict__ lin_b,   // [10]
    float* __restrict__ out)           // [B, 10]
{
    // rows 0..3: qf (A, m=batch); rows 4..13: lin_w bf16 (B, n=output);
    // rows 14..19: allocated, read only into discarded C entries.
    __shared__ __align__(16) unsigned short lds[20 * RS];   // 32320 B
    __shared__ __align__(16) float red_s[4 * 16 * 16];      // 4096 B
    __shared__ float lg_s[BPB * 10];
    __shared__ float off_s[BPB];

    const int t = threadIdx.x;
    const int b0 = blockIdx.x * BPB;

    // ---- zero pad cols [784,808) of all 20 rows (12 dwords x 20 rows)
    for (int i = t; i < 20 * 12; i += 256) {
        const int r = i / 12, d = i - 12 * r;
        ((unsigned*)(lds + r * RS + 784))[d] = 0u;
    }

    // ---- stage lin_w -> bf16 B rows (abs rows 4..13)
    {
        const float4* lw4 = (const float4*)lin_w;   // 1960 float4
        for (int i = t; i < 1960; i += 256) {
            const int o = i / 196;
            const int k0 = 4 * (i - 196 * o);
            const float4 v = lw4[i];
            const unsigned lo = f2bf(v.x) | ((unsigned)f2bf(v.y) << 16);
            const unsigned hi = f2bf(v.z) | ((unsigned)f2bf(v.w) << 16);
            *(uint2*)(lds + (4 + o) * RS + k0) = make_uint2(lo, hi);
        }
    }

    const float th0 = q_theta[0];
    const float ct1 = __cosf(q_theta[1]);
    const float th3 = q_theta[3];

    // ---- features: one conv output per thread, i = b*784 + c*196 + s,
    // lanes dense in s -> coalesced x loads; quad = one patch's 4 wires.
    auto feature = [&](int i) {
        const int b = i / 784;
        const int r = i - 784 * b;          // c*196 + s
        const int c = r / 196;
        const int s = r - 196 * c;
        const int k = i & 3;                // wire (784, 196 mult of 4)
        const int h = s / 14;
        const int w2 = s - 14 * h;

        const float* xp = x + (size_t)(b0 + b) * 784 + 56 * h + 2 * w2;
        const float2 top = *(const float2*)xp;
        const float2 bot = *(const float2*)(xp + 28);
        const float4 cw = ((const float4*)conv_w)[c];
        const float a = conv_b[c] + top.x * cw.x + top.y * cw.y
                                  + bot.x * cw.z + bot.y * cw.w;

        const float shift = (k == 0) ? th0 : ((k == 3) ? th3 : 0.0f);
        float z = __cosf(a + shift);
        z = (k == 1) ? z * ct1 : z;

        // register-only quad share (wires live on consecutive lanes)
        const float z0 = quadb<0x00>(z);
        const float z1 = quadb<0x55>(z);
        const float z2 = quadb<0xAA>(z);
        const float z3 = quadb<0xFF>(z);

        const float m01 = z0 * z1;
        const float f = (k == 0) ? z0
                      : (k == 1) ? m01
                      : (k == 2) ? m01 * z2
                                 : z1 * z2 * z3;
        lds[b * RS + r] = f2bf(f);          // dense 2B qf write
    };

#pragma unroll
    for (int j = 0; j < 12; ++j) feature(t + 256 * j);
    if (t < 64) feature(3072 + t);          // tail: whole wave 0 active

    __syncthreads();

    // ---- MFMA: K = 25 interleaved 32-tiles; wave wv takes k = 32*(wv+4*kk)
    {
        const int wv = t >> 6;
        const int lane = t & 63;
        const int mrow = lane & 15;
        const int qd = lane >> 4;
        const unsigned short* qrow = lds + mrow * RS + 8 * qd;        // A
        const unsigned short* wrow = lds + (4 + mrow) * RS + 8 * qd;  // B
        float4v acc = {0.f, 0.f, 0.f, 0.f};
#pragma unroll
        for (int kk = 0; kk < 7; ++kk) {
            const int k = 32 * (wv + 4 * kk);
            if (k < 800) {
                const short8 af = *(const short8*)(qrow + k);
                const short8 bf = *(const short8*)(wrow + k);
                acc = __builtin_amdgcn_mfma_f32_16x16x32_bf16(af, bf, acc, 0, 0, 0);
            }
        }
        // C: col = lane&15 (=n), rows = qd*4+reg (=m). Store [wv][n][m].
        *(float4v*)(red_s + (wv * 16 + mrow) * 16 + qd * 4) = acc;
    }

    __syncthreads();

    // ---- reduce 4 partial tiles; keep m<4 (batch), n<10 (outputs)
    {
        const int n = t >> 4;
        const int m = t & 15;
        if (m < BPB && n < 10) {
            const float s = red_s[0 * 256 + n * 16 + m] + red_s[1 * 256 + n * 16 + m]
                          + red_s[2 * 256 + n * 16 + m] + red_s[3 * 256 + n * 16 + m];
            lg_s[m * 10 + n] = s + lin_b[n];
        }
    }

    __syncthreads();

    if (t < BPB) {
        float mx = -INFINITY;
#pragma unroll
        for (int j = 0; j < 10; ++j) mx = fmaxf(mx, lg_s[t * 10 + j]);
        float sum = 0.0f;
#pragma unroll
        for (int j = 0; j < 10; ++j) sum += __expf(lg_s[t * 10 + j] - mx);
        off_s[t] = mx + __logf(sum);
    }

    __syncthreads();

    if (t < BPB * 10) {
        out[(size_t)b0 * 10 + t] = lg_s[t] - off_s[t / 10];
    }
}

extern "C" void kernel_launch(void* const* d_in, const int* in_sizes, int n_in,
                              void* d_out, int out_size, void* d_ws, size_t ws_size,
                              hipStream_t stream) {
    const float* x       = (const float*)d_in[0];
    const float* conv_w  = (const float*)d_in[1];
    const float* conv_b  = (const float*)d_in[2];
    const float* q_theta = (const float*)d_in[3];
    const float* lin_w   = (const float*)d_in[4];
    const float* lin_b   = (const float*)d_in[5];
    float* out = (float*)d_out;

    hqe_kernel<<<dim3(GRID), dim3(256), 0, stream>>>(x, conv_w, conv_b, q_theta,
                                                     lin_w, lin_b, out);
}